// Round 13
// baseline (212.064 us; speedup 1.0000x reference)
//
#include <hip/hip_runtime.h>
#include <cstdint>

constexpr int Sd = 1024;
constexpr int Td = 48;
constexpr int NTAG = 45;    // normal tags 0..44
constexpr int START_ = 45;
constexpr int STOP_ = 46;

__device__ __forceinline__ int rfl_i(int x) { return __builtin_amdgcn_readfirstlane(x); }

// DPP-fused MAC: acc += rot(s, N) * ee   (rotation folded into the FMA)
#define FMD(acc, s, ee, N) \
    asm("v_fmac_f32 %0, %1, %2 row_ror:" #N " row_mask:0xf bank_mask:0xf" \
        : "+v"(acc) : "v"(s), "v"(ee))
// DPP-fused MUL (chain init): acc = rot(s, N) * ee
#define MULD(acc, s, ee, N) \
    asm("v_mul_f32 %0, %1, %2 row_ror:" #N " row_mask:0xf bank_mask:0xf" \
        : "=v"(acc) : "v"(s), "v"(ee))

// 16 rotations of one slot dotted with its E block; two 8-deep chains
#define SLOT16(s, E, aA, aB) do {                                              \
    aA = (s) * E[0];                                                           \
    FMD(aA, s, E[1], 1);  FMD(aA, s, E[2], 2);  FMD(aA, s, E[3], 3);           \
    FMD(aA, s, E[4], 4);  FMD(aA, s, E[5], 5);  FMD(aA, s, E[6], 6);           \
    FMD(aA, s, E[7], 7);                                                       \
    MULD(aB, s, E[8], 8);                                                      \
    FMD(aB, s, E[9], 9);  FMD(aB, s, E[10], 10); FMD(aB, s, E[11], 11);        \
    FMD(aB, s, E[12], 12); FMD(aB, s, E[13], 13); FMD(aB, s, E[14], 14);       \
    FMD(aB, s, E[15], 15);                                                     \
} while (0)

// One exp-domain chain step (R12-validated arithmetic, parameterized state):
//   slot0 = vv; slot1/2 = ds_bpermute vv[(lane+16/32)%48]
//   48 DPP-fused MACs vs E0/E1/E2 (preloaded permuted); PF pre-exp'd;
//   scalar power-of-2 renorm via readfirstlane (exact).
#define STEPC(vv, uff, kxx, scc, LL, E0, E1, E2, PF, WANTUF) do {              \
    int _vi = __float_as_int(vv);                                              \
    int _b1 = __builtin_amdgcn_ds_bpermute(a16, _vi);                          \
    int _b2 = __builtin_amdgcn_ds_bpermute(a32, _vi);                          \
    float _s1 = __int_as_float(_b1), _s2 = __int_as_float(_b2);                \
    float a0A, a0B, a1A, a1B, a2A, a2B;                                        \
    SLOT16(vv,  E0, a0A, a0B);                                                 \
    SLOT16(_s1, E1, a1A, a1B);                                                 \
    SLOT16(_s2, E2, a2A, a2B);                                                 \
    float tot_ = ((a0A + a0B) + (a1A + a1B)) + (a2A + a2B);                    \
    LL += kxx;                                                                 \
    if (WANTUF) uff = tot_ * scc;                                              \
    vv = tot_ * ((PF) * scc);                                                  \
    { int _kb = rfl_i(__float_as_int(vv));                                     \
      kxx = ((_kb >> 23) & 0xFF) - 127;                                        \
      scc = __int_as_float((127 - kxx) << 23); }                               \
} while (0)

// one superstep = one fwd step + one bwd step (independent register streams)
#define SUPER(PFF, PFU) do {                                                   \
    STEPC(vF, ufF, kxF, scF, LF, eF0, eF1, eF2, PFF, false);                   \
    STEPC(vU, ufU, kxU, scU, LU, eU0, eU1, eU2, PFU, true);                    \
} while (0)

#define ADVF() do { if (tF < Sd - 1) { pcF += Td; ++tF; } } while (0)
#define ADVU() do { if (tU > 0)      { pcU -= Td; --tU; } } while (0)

__launch_bounds__(64, 1)
__global__ void crf_fb(const float* __restrict__ feats,
                       const float* __restrict__ masks,
                       const int* __restrict__ tags,
                       const float* __restrict__ trans,
                       float* __restrict__ out)
{
    __shared__ float tl[Td * Td];
    const int lane = threadIdx.x;
    const int b = blockIdx.x;

    for (int i = lane; i < Td * Td; i += 64) tl[i] = trans[i];
    __syncthreads();

    const size_t bS = (size_t)b * Sd;

    // ---- length from prefix mask (scalar) ----
    float c = 0.f;
    for (int t = lane; t < Sd; t += 64) c += masks[bS + t];
#pragma unroll
    for (int off = 32; off; off >>= 1) c += __shfl_xor(c, off);
    int len = (int)(c + 0.5f);
    if (len < 1) len = 1;
    len = rfl_i(len);

    // ---- gold score ----
    float g = 0.f;
    for (int t = lane; t < len; t += 64) {
        const int tag  = tags[bS + t];
        const int prev = (t == 0) ? START_ : tags[bS + t - 1];
        g += feats[(bS + t) * Td + tag] + tl[tag * Td + prev];
    }
#pragma unroll
    for (int off = 32; off; off >>= 1) g += __shfl_xor(g, off);
    g += tl[STOP_ * Td + tags[bS + len - 1]];

    // ---- runtime-detect row_ror direction (validated R9-R12) ----
    const int p = lane & 15;
    const int qd = __builtin_amdgcn_mov_dpp(p, 0x121, 0xF, 0xF, false); // row_ror:1
    const int d = (qd == ((p + 1) & 15)) ? 1 : -1;
    const int r0 = (lane >> 4) & 3;                  // own 16-block (3 = idle lanes)

    // ---- bpermute byte-addresses for the 3-block rotation gather ----
    const int a16 = (((lane + 16) % Td) << 2);
    const int a32 = (((lane + 32) % Td) << 2);

    // ---- E rows (fwd) AND E^T rows (bwd), gather-permuted scalar order ----
    float eF0[16], eF1[16], eF2[16], eU0[16], eU1[16], eU2[16];
#pragma unroll
    for (int h = 0; h < 3; ++h) {
        float* dF = (h == 0) ? eF0 : (h == 1) ? eF1 : eF2;
        float* dU = (h == 0) ? eU0 : (h == 1) ? eU1 : eU2;
        const int blk = 16 * ((r0 + h) % 3);
#pragma unroll
        for (int i = 0; i < 16; ++i) {
            const int cc = blk + ((p + d * i) & 15);
            dF[i] = (lane < NTAG) ? __expf(tl[lane * Td + cc]) : 0.f; // sink rows 0
            dU[i] = (lane < Td)   ? __expf(tl[cc * Td + lane]) : 0.f;
        }
    }

    // ---- chain inits ----
    const int lidx = (lane < Td) ? lane : 0;
    const float* frow = feats + bS * Td;
    const int Fh = (len + 1) >> 1;
    const int actF = rfl_i(Fh - 1);
    const int actU = rfl_i(len - Fh);                // actU - actF in {0,1}

    const float einitF = (lane < NTAG) ? __expf(tl[lane * Td + START_]) : 0.f;
    const float wstop  = (lane < Td)   ? __expf(tl[STOP_ * Td + lane])  : 0.f;

    float vF = __expf(frow[lidx]) * einitF;                          // time 0
    float vU = wstop * __expf(frow[(size_t)(len - 1) * Td + lidx]);  // time len-1
    float ufF;                                                       // dummy
    float ufU = wstop;                                               // actU==0 case
    int LF = 0, LU = 0, kxF, kxU; float scF, scU;
    { int kb = rfl_i(__float_as_int(vF)); kxF = ((kb >> 23) & 0xFF) - 127;
      scF = __int_as_float((127 - kxF) << 23); }
    { int kb = rfl_i(__float_as_int(vU)); kxU = ((kb >> 23) & 0xFF) - 127;
      scU = __int_as_float((127 - kxU) << 23); }

    // ---- emission prefetch: 4 slots per chain, PRE-EXP'd; scalar advance ----
    // fwd superstep s consumes e_{s+1}; bwd superstep s consumes e_{len-2-s}
    auto eiF = [&](int s) -> int { int t = 1 + s; return t < Sd ? t : (Sd - 1); };
    auto eiU = [&](int s) -> int { int t = len - 2 - s; return t > 0 ? t : 0; };
    float pfF0 = __expf(frow[(size_t)eiF(0) * Td + lidx]);
    float pfF1 = __expf(frow[(size_t)eiF(1) * Td + lidx]);
    float pfF2 = __expf(frow[(size_t)eiF(2) * Td + lidx]);
    float pfF3 = __expf(frow[(size_t)eiF(3) * Td + lidx]);
    float pfU0 = __expf(frow[(size_t)eiU(0) * Td + lidx]);
    float pfU1 = __expf(frow[(size_t)eiU(1) * Td + lidx]);
    float pfU2 = __expf(frow[(size_t)eiU(2) * Td + lidx]);
    float pfU3 = __expf(frow[(size_t)eiU(3) * Td + lidx]);
    int tF = eiF(4), tU = eiU(4);
    const float* pcF = frow + (size_t)tF * Td;
    const float* pcU = frow + (size_t)tU * Td;

    const int common = actF;                         // min(actF, actU)
    int k = 0;
    while (k + 4 <= common) {
        SUPER(pfF0, pfU0); pfF0 = __expf(pcF[lidx]); ADVF(); pfU0 = __expf(pcU[lidx]); ADVU();
        SUPER(pfF1, pfU1); pfF1 = __expf(pcF[lidx]); ADVF(); pfU1 = __expf(pcU[lidx]); ADVU();
        SUPER(pfF2, pfU2); pfF2 = __expf(pcF[lidx]); ADVF(); pfU2 = __expf(pcU[lidx]); ADVU();
        SUPER(pfF3, pfU3); pfF3 = __expf(pcF[lidx]); ADVF(); pfU3 = __expf(pcU[lidx]); ADVU();
        k += 4;
    }
    if (k < common) { SUPER(pfF0, pfU0); ++k; }
    if (k < common) { SUPER(pfF1, pfU1); ++k; }
    if (k < common) { SUPER(pfF2, pfU2); ++k; }
    if (actU > common) {                             // at most one extra bwd step
        const int r = common & 3;
        const float pfx = (r == 0) ? pfU0 : (r == 1) ? pfU1 : (r == 2) ? pfU2 : pfU3;
        STEPC(vU, ufU, kxU, scU, LU, eU0, eU1, eU2, pfx, true);
    }

    // ---- meeting: dot(vF, ufU) in-wave; answer directly ----
    float dt = vF * ufU;
#pragma unroll
    for (int off = 32; off; off >>= 1) dt += __shfl_xor(dt, off);

    if (lane == 0) {
        const float ln2 = 0.6931471805599453f;
        out[b] = (float)(LF + LU) * ln2 + __logf(dt) - g;
    }
}

extern "C" void kernel_launch(void* const* d_in, const int* in_sizes, int n_in,
                              void* d_out, int out_size, void* d_ws, size_t ws_size,
                              hipStream_t stream) {
    const float* feats = (const float*)d_in[0];
    const float* masks = (const float*)d_in[1];
    const int*   tags  = (const int*)d_in[2];
    const float* trans = (const float*)d_in[3];
    float* outp = (float*)d_out;

    const int Bn = in_sizes[1] / Sd;                 // B = 512
    crf_fb<<<dim3(Bn), dim3(64), 0, stream>>>(feats, masks, tags, trans, outp);
}